// Round 5
// baseline (556.120 us; speedup 1.0000x reference)
//
#include <hip/hip_runtime.h>
#include <hip/hip_bf16.h>
#include <math.h>

typedef __bf16 bf16_t;
typedef __bf16 bf16x8 __attribute__((ext_vector_type(8)));
typedef float f32x4 __attribute__((ext_vector_type(4)));
typedef unsigned short u16;

#define NB   40
#define NT   20
#define FEA  200
#define HD   1024
#define NOUT 1095
#define NL   12
#define M_ROWS 800      // NB*NT
#define UPITCH 196      // fp32 pitch for U in LDS (192 + 4 pad)

#define FBUF 49152      // fused ring-3 buf: A 192x64x2 (24576, rows padded 160->192) + B 192x64x2 (24576)
#define GBUF 24576      // dense ring-4 buf: A 16KB + B 8KB

// ---------------------------------------------------------------------------
// Transpose+convert: src fp32 logical [srcK][srcN] -> dst bf16 [Np][Kp],
// dst[n][k] = (k<srcK && n<srcN) ? src[k][n] : 0.
// ---------------------------------------------------------------------------
__global__ __launch_bounds__(256)
void transpose_convert(const float* __restrict__ src, bf16_t* __restrict__ dst,
                       int srcK, int srcN, int Kp, int Np)
{
    __shared__ u16 tile[64 * 66];
    const int t = threadIdx.x;
    src += (size_t)blockIdx.z * srcK * srcN;
    dst += (size_t)blockIdx.z * Np * Kp;
    const int n0 = blockIdx.x << 6, k0 = blockIdx.y << 6;
    {
        const int nl = t & 63, kb = (t >> 6) << 4;
        const int gn = n0 + nl;
        #pragma unroll
        for (int j = 0; j < 16; j++) {
            const int gk = k0 + kb + j;
            float v = (gk < srcK && gn < srcN) ? src[(size_t)gk * srcN + gn] : 0.f;
            bf16_t b = (bf16_t)v;
            tile[nl * 66 + kb + j] = *(const u16*)&b;
        }
    }
    __syncthreads();
    {
        const int nl = t >> 2, kg = (t & 3) << 4;
        const unsigned* tp = (const unsigned*)tile;
        const int dw = nl * 33 + (kg >> 1);
        uint4 v0, v1;
        v0.x = tp[dw+0]; v0.y = tp[dw+1]; v0.z = tp[dw+2]; v0.w = tp[dw+3];
        v1.x = tp[dw+4]; v1.y = tp[dw+5]; v1.z = tp[dw+6]; v1.w = tp[dw+7];
        bf16_t* dp = dst + (size_t)(n0 + nl) * Kp + k0 + kg;
        *(uint4*)dp = v0;
        *(uint4*)(dp + 8) = v1;
    }
}

// x [800][200] fp32 -> xb [800][256] bf16, zero-padded K.
__global__ __launch_bounds__(256)
void convert_pad_x(const float* __restrict__ src, bf16_t* __restrict__ dst)
{
    const int m = blockIdx.x, k = threadIdx.x;
    dst[m * 256 + k] = (bf16_t)((k < FEA) ? src[(size_t)m * FEA + k] : 0.f);
}

// ---------------------------------------------------------------------------
// LDS-tiled dense GEMM, ring-4 counted-vmcnt pipeline (unchanged from R4).
// BM=128, BN=64, BK=64; 4 waves, each a 64x32 quadrant.
// ---------------------------------------------------------------------------
template<bool OUT_F32, bool RELU>
__global__ __launch_bounds__(256)
void gemm_tiled(const bf16_t* __restrict__ A, const bf16_t* __restrict__ Bt,
                const float* __restrict__ bias, void* __restrict__ C,
                int M, int Nstore, int Ks)
{
    extern __shared__ char lds[];           // [4][GBUF]
    const int tid = threadIdx.x;
    const int w = tid >> 6, lane = tid & 63, quad = lane >> 4, l16 = lane & 15;
    const int n0 = blockIdx.x << 6;
    const int m0 = blockIdx.y << 7;
    const int wr = w >> 1, wc = w & 1;

    const int lrow  = lane >> 3;
    const int gslot = ((lane & 7) ^ lrow) << 3;
    const bf16_t* aSrc[4];
    const bf16_t* bSrc[2];
    #pragma unroll
    for (int i = 0; i < 4; i++) {
        int r = m0 + (w * 4 + i) * 8 + lrow;
        if (r > M - 1) r = M - 1;
        aSrc[i] = A + (size_t)r * Ks + gslot;
    }
    #pragma unroll
    for (int i = 0; i < 2; i++)
        bSrc[i] = Bt + (size_t)(n0 + (w * 2 + i) * 8 + lrow) * Ks + gslot;

    f32x4 acc[4][2];
    #pragma unroll
    for (int m = 0; m < 4; m++)
        #pragma unroll
        for (int n = 0; n < 2; n++) acc[m][n] = (f32x4){0.f, 0.f, 0.f, 0.f};

    const int nkt = Ks >> 6;

    #define STAGE(kt) do {                                                     \
        const int _k0 = (kt) << 6;                                             \
        char* _b = lds + ((kt) & 3) * GBUF;                                    \
        _Pragma("unroll")                                                      \
        for (int _i = 0; _i < 4; _i++)                                         \
            __builtin_amdgcn_global_load_lds(                                  \
                (const __attribute__((address_space(1))) void*)(aSrc[_i] + _k0),\
                (__attribute__((address_space(3))) void*)(_b + (w * 4 + _i) * 1024), \
                16, 0, 0);                                                     \
        _Pragma("unroll")                                                      \
        for (int _i = 0; _i < 2; _i++)                                         \
            __builtin_amdgcn_global_load_lds(                                  \
                (const __attribute__((address_space(1))) void*)(bSrc[_i] + _k0),\
                (__attribute__((address_space(3))) void*)(_b + 16384 + (w * 2 + _i) * 1024), \
                16, 0, 0);                                                     \
    } while (0)

    STAGE(0);
    if (nkt > 1) STAGE(1);

    for (int kt = 0; kt < nkt; kt++) {
        if (kt + 2 < nkt) STAGE(kt + 2);
        const int rem = nkt - 1 - kt;
        if (rem >= 2)      asm volatile("s_waitcnt vmcnt(12)" ::: "memory");
        else if (rem == 1) asm volatile("s_waitcnt vmcnt(6)"  ::: "memory");
        else               asm volatile("s_waitcnt vmcnt(0)"  ::: "memory");
        __builtin_amdgcn_s_barrier();

        const char* ab = lds + (kt & 3) * GBUF;
        #pragma unroll
        for (int kk = 0; kk < 2; kk++) {
            const int ts = (kk << 2) + quad;
            bf16x8 a[4], b[2];
            #pragma unroll
            for (int m = 0; m < 4; m++) {
                const int r = wr * 64 + m * 16 + l16;
                a[m] = *(const bf16x8*)(ab + r * 128 + ((ts ^ (r & 7)) << 4));
            }
            #pragma unroll
            for (int n = 0; n < 2; n++) {
                const int r = wc * 32 + n * 16 + l16;
                b[n] = *(const bf16x8*)(ab + 16384 + r * 128 + ((ts ^ (r & 7)) << 4));
            }
            #pragma unroll
            for (int m = 0; m < 4; m++)
                #pragma unroll
                for (int n = 0; n < 2; n++)
                    acc[m][n] = __builtin_amdgcn_mfma_f32_16x16x32_bf16(a[m], b[n], acc[m][n], 0, 0, 0);
        }
    }
    #undef STAGE

    #pragma unroll
    for (int n = 0; n < 2; n++) {
        const int col = n0 + wc * 32 + n * 16 + l16;
        if (col >= Nstore) continue;
        const float bv = bias ? bias[col] : 0.f;
        #pragma unroll
        for (int m = 0; m < 4; m++) {
            #pragma unroll
            for (int i = 0; i < 4; i++) {
                const int mg = m0 + wr * 64 + m * 16 + quad * 4 + i;
                if (mg < M) {
                    float v = acc[m][n][i] + bv;
                    if (RELU) v = v > 0.f ? v : 0.f;
                    if (OUT_F32) ((float*)C)[(size_t)mg * Nstore + col] = v;
                    else         ((bf16_t*)C)[(size_t)mg * Nstore + col] = (bf16_t)v;
                }
            }
        }
    }
}

// ---------------------------------------------------------------------------
// Fused SRU layer, 512 threads, M=160 (8 batches) x N=192, K=1024, nkt=16.
// Halves weight redundancy (5 row-groups instead of 10) and gives 2
// waves/SIMD. 8 waves = 2 row-halves (rh) x 4 col-quarters (wq); per wave
// 5x3 fragment grid (same as R4). Ring-3 x 48KB LDS, depth-1 counted-vmcnt:
// per iter [vmcnt(6); barrier; compute kt; stage kt+2]. Stage target
// (kt+2)%3 was last read at compute(kt-1), finished before barrier(kt) ->
// race-free. A rows padded 160->192 (24 chunks) so every wave stages
// exactly 3 A + 3 B chunks -> uniform vmcnt. Post-loop barrier before the
// U-epilogue (Ul overlaps the ring). Recurrence: 8 batches x 64 cols =
// 512 threads, fully unrolled, branch-free tanh via __expf.
// Dynamic LDS 147456 B.
// ---------------------------------------------------------------------------
__global__ __launch_bounds__(512)
void sru_layer_fused(const bf16_t* __restrict__ hin, bf16_t* __restrict__ hout,
                     const bf16_t* __restrict__ Wt, const float* __restrict__ c0,
                     const float* __restrict__ bvec, float* __restrict__ cout)
{
    extern __shared__ char lds_raw[];       // [3][FBUF]
    const int tid = threadIdx.x;
    const int w = tid >> 6, lane = tid & 63, quad = lane >> 4, l16 = lane & 15;
    const int rh = w >> 2, wq = w & 3;      // row half, col quarter
    const int n0 = blockIdx.x << 6;         // h-col block (16)
    const int m0 = blockIdx.y * 160;        // 8 batches  (5)

    const int lrow  = lane >> 3;
    const int gslot = ((lane & 7) ^ lrow) << 3;

    // A: 24 chunks of 8 rows (rows 160..191 clamp-duplicate row 159, never
    // read back); wave w stages chunks w*3+i.
    const bf16_t* aSrc[3];
    #pragma unroll
    for (int i = 0; i < 3; i++) {
        int r = (w * 3 + i) * 8 + lrow;     // 0..191
        if (r > 159) r = 159;
        aSrc[i] = hin + (size_t)(m0 + r) * HD + gslot;
    }
    // B: 24 chunks of 8 rows; wave w stages chunks w*3+i. B row rb (0..191)
    // = Wt row (rb>>6)*HD + n0 + (rb&63)   [U col rb: gate rb>>6].
    const bf16_t* bSrc[3];
    #pragma unroll
    for (int i = 0; i < 3; i++) {
        const int rb = (w * 3 + i) * 8 + lrow;
        bSrc[i] = Wt + (size_t)((rb >> 6) * HD + n0 + (rb & 63)) * HD + gslot;
    }

    f32x4 acc[5][3];
    #pragma unroll
    for (int m = 0; m < 5; m++)
        #pragma unroll
        for (int n = 0; n < 3; n++) acc[m][n] = (f32x4){0.f, 0.f, 0.f, 0.f};

    #define STAGEF(kt) do {                                                    \
        const int _k0 = (kt) << 6;                                             \
        char* _b = lds_raw + ((kt) % 3) * FBUF;                                \
        _Pragma("unroll")                                                      \
        for (int _i = 0; _i < 3; _i++)                                         \
            __builtin_amdgcn_global_load_lds(                                  \
                (const __attribute__((address_space(1))) void*)(aSrc[_i] + _k0), \
                (__attribute__((address_space(3))) void*)(_b + (w * 3 + _i) * 1024), \
                16, 0, 0);                                                     \
        _Pragma("unroll")                                                      \
        for (int _i = 0; _i < 3; _i++)                                         \
            __builtin_amdgcn_global_load_lds(                                  \
                (const __attribute__((address_space(1))) void*)(bSrc[_i] + _k0), \
                (__attribute__((address_space(3))) void*)(_b + 24576 + (w * 3 + _i) * 1024), \
                16, 0, 0);                                                     \
    } while (0)

    STAGEF(0);
    STAGEF(1);

    for (int kt = 0; kt < 16; kt++) {
        if (kt < 15) asm volatile("s_waitcnt vmcnt(6)" ::: "memory");
        else         asm volatile("s_waitcnt vmcnt(0)" ::: "memory");
        __builtin_amdgcn_s_barrier();

        const char* ab = lds_raw + (kt % 3) * FBUF;
        const char* bb = ab + 24576;
        #pragma unroll
        for (int kk = 0; kk < 2; kk++) {
            const int ts = (kk << 2) + quad;
            bf16x8 a[5], b[3];
            #pragma unroll
            for (int m = 0; m < 5; m++) {
                const int r = rh * 80 + m * 16 + l16;
                a[m] = *(const bf16x8*)(ab + r * 128 + ((ts ^ (r & 7)) << 4));
            }
            #pragma unroll
            for (int n = 0; n < 3; n++) {
                const int rb = (wq * 3 + n) * 16 + l16;
                b[n] = *(const bf16x8*)(bb + rb * 128 + ((ts ^ (rb & 7)) << 4));
            }
            #pragma unroll
            for (int m = 0; m < 5; m++)
                #pragma unroll
                for (int n = 0; n < 3; n++)
                    acc[m][n] = __builtin_amdgcn_mfma_f32_16x16x32_bf16(a[m], b[n], acc[m][n], 0, 0, 0);
        }
        if (kt + 2 < 16) STAGEF(kt + 2);
    }
    #undef STAGEF

    // Ul (125KB) overlaps the ring incl. the last tile's buffer -> full
    // barrier before overwriting.
    __syncthreads();

    float* Ul = (float*)lds_raw;                 // [160][UPITCH]
    #pragma unroll
    for (int m = 0; m < 5; m++)
        #pragma unroll
        for (int n = 0; n < 3; n++) {
            const int col = (wq * 3 + n) * 16 + l16;
            #pragma unroll
            for (int i = 0; i < 4; i++)
                Ul[(rh * 80 + m * 16 + quad * 4 + i) * UPITCH + col] = acc[m][n][i];
        }
    __syncthreads();

    // recurrence: thread = (local batch bl 0..7, col nn)
    const int bl = tid >> 6, nn = tid & 63, bg = blockIdx.y * 8 + bl;
    float c = c0[(size_t)bg * HD + n0 + nn];
    const float bfb = bvec[n0 + nn], brb = bvec[HD + n0 + nn];
    #pragma unroll
    for (int t = 0; t < NT; t++) {
        const float* u = &Ul[(bl * NT + t) * UPITCH];
        const float xt = u[nn];
        const float uf = u[64 + nn];
        const float ur = u[128 + nn];
        const float f = 1.f / (1.f + __expf(-(uf + bfb)));
        const float r = 1.f / (1.f + __expf(-(ur + brb)));
        c = f * c + (1.f - f) * xt;
        // branch-free tanh: exact identity, fp32 rounding only
        const float e  = __expf(-2.f * fabsf(c));
        float th = (1.f - e) / (1.f + e);
        th = (c < 0.f) ? -th : th;
        const size_t gi = (size_t)(bg * NT + t) * HD + n0 + nn;
        const float hp = (float)hin[gi];
        hout[gi] = (bf16_t)(r * th + (1.f - r) * hp);
    }
    cout[(size_t)bg * HD + n0 + nn] = c;
}

// ---------------------------------------------------------------------------
extern "C" void kernel_launch(void* const* d_in, const int* in_sizes, int n_in,
                              void* d_out, int out_size, void* d_ws, size_t ws_size,
                              hipStream_t stream)
{
    const float* x      = (const float*)d_in[0];
    const float* hidden = (const float*)d_in[1];
    const float* W1     = (const float*)d_in[2];
    const float* b1     = (const float*)d_in[3];
    const float* sruW   = (const float*)d_in[4];
    const float* srub   = (const float*)d_in[5];
    const float* W3     = (const float*)d_in[6];
    const float* b3     = (const float*)d_in[7];
    const float* W4     = (const float*)d_in[8];
    const float* b4     = (const float*)d_in[9];

    float* out     = (float*)d_out;
    float* hid_out = out + (size_t)M_ROWS * NOUT;          // [12,40,1024] fp32

    // h0 (bf16) lives in d_out's out0 region (dead until final GEMM overwrites).
    bf16_t* h0 = (bf16_t*)d_out;

    // raise dynamic-LDS caps (host-side; graph-capture safe, proven R3/R4)
    hipFuncSetAttribute((const void*)sru_layer_fused,
                        hipFuncAttributeMaxDynamicSharedMemorySize, 3 * FBUF);
    hipFuncSetAttribute((const void*)gemm_tiled<false, false>,
                        hipFuncAttributeMaxDynamicSharedMemorySize, 4 * GBUF);
    hipFuncSetAttribute((const void*)gemm_tiled<false, true>,
                        hipFuncAttributeMaxDynamicSharedMemorySize, 4 * GBUF);
    hipFuncSetAttribute((const void*)gemm_tiled<true, false>,
                        hipFuncAttributeMaxDynamicSharedMemorySize, 4 * GBUF);

    char* ws = (char*)d_ws;
    const size_t SZ_WT  = (size_t)NL * 3 * HD * HD * 2;    // 75,497,472
    const size_t SZ_W1  = (size_t)HD * 256 * 2;
    const size_t SZ_W3  = (size_t)HD * HD * 2;
    const size_t SZ_W4  = (size_t)1152 * HD * 2;
    const size_t SZ_XB  = (size_t)M_ROWS * 256 * 2;
    const size_t SZ_H   = (size_t)M_ROWS * HD * 2;
    const size_t SLOT   = (size_t)3 * HD * HD * 2;
    const size_t FAST_NEED = SZ_WT + SZ_W1 + SZ_W3 + SZ_W4 + SZ_XB + 2 * SZ_H;
    const bool fast = ws_size >= FAST_NEED;

    const dim3 blk(256);
    const dim3 blkf(512);
    const int GY = (M_ROWS + 127) >> 7;                    // 7 row-blocks

    if (fast) {
        bf16_t* wt  = (bf16_t*)ws;
        bf16_t* w1t = (bf16_t*)(ws + SZ_WT);
        bf16_t* w3t = (bf16_t*)(ws + SZ_WT + SZ_W1);
        bf16_t* w4t = (bf16_t*)(ws + SZ_WT + SZ_W1 + SZ_W3);
        bf16_t* xb  = (bf16_t*)(ws + SZ_WT + SZ_W1 + SZ_W3 + SZ_W4);
        bf16_t* h1  = (bf16_t*)(ws + SZ_WT + SZ_W1 + SZ_W3 + SZ_W4 + SZ_XB);
        bf16_t* g   = (bf16_t*)(ws + SZ_WT + SZ_W1 + SZ_W3 + SZ_W4 + SZ_XB + SZ_H);

        convert_pad_x<<<M_ROWS, blk, 0, stream>>>(x, xb);
        transpose_convert<<<dim3(16, 4, 1),  blk, 0, stream>>>(W1,   w1t, FEA, HD,    256, HD);
        transpose_convert<<<dim3(48, 16, NL), blk, 0, stream>>>(sruW, wt,  HD,  3*HD, HD,  3*HD);
        transpose_convert<<<dim3(16, 16, 1), blk, 0, stream>>>(W3,   w3t, HD,  HD,   HD,  HD);
        transpose_convert<<<dim3(18, 16, 1), blk, 0, stream>>>(W4,   w4t, HD,  NOUT, HD,  1152);

        gemm_tiled<false, false><<<dim3(16, GY), blk, 4 * GBUF, stream>>>(xb, w1t, b1, h0, M_ROWS, HD, 256);

        for (int l = 0; l < NL; l++) {
            const bf16_t* hi = (l & 1) ? h1 : h0;
            bf16_t*       ho = (l & 1) ? h0 : h1;
            sru_layer_fused<<<dim3(16, 5), blkf, 3 * FBUF, stream>>>(
                hi, ho, wt + (size_t)l * 3 * HD * HD,
                hidden + (size_t)l * NB * HD, srub + (size_t)l * 2 * HD,
                hid_out + (size_t)l * NB * HD);
        }
        gemm_tiled<false, true><<<dim3(16, GY), blk, 4 * GBUF, stream>>>(h0, w3t, b3, g, M_ROWS, HD, HD);
        gemm_tiled<true, false><<<dim3(18, GY), blk, 4 * GBUF, stream>>>(g, w4t, b4, out, M_ROWS, NOUT, HD);
    } else {
        bf16_t* slot = (bf16_t*)ws;
        bf16_t* xb   = (bf16_t*)(ws + SLOT);
        bf16_t* h1   = (bf16_t*)(ws + SLOT + SZ_XB);
        bf16_t* g    = (bf16_t*)(ws + SLOT + SZ_XB + SZ_H);

        convert_pad_x<<<M_ROWS, blk, 0, stream>>>(x, xb);
        transpose_convert<<<dim3(16, 4, 1), blk, 0, stream>>>(W1, slot, FEA, HD, 256, HD);
        gemm_tiled<false, false><<<dim3(16, GY), blk, 4 * GBUF, stream>>>(xb, slot, b1, h0, M_ROWS, HD, 256);

        for (int l = 0; l < NL; l++) {
            transpose_convert<<<dim3(48, 16, 1), blk, 0, stream>>>(
                sruW + (size_t)l * HD * 3 * HD, slot, HD, 3*HD, HD, 3*HD);
            const bf16_t* hi = (l & 1) ? h1 : h0;
            bf16_t*       ho = (l & 1) ? h0 : h1;
            sru_layer_fused<<<dim3(16, 5), blkf, 3 * FBUF, stream>>>(
                hi, ho, slot,
                hidden + (size_t)l * NB * HD, srub + (size_t)l * 2 * HD,
                hid_out + (size_t)l * NB * HD);
        }
        transpose_convert<<<dim3(16, 16, 1), blk, 0, stream>>>(W3, slot, HD, HD, HD, HD);
        gemm_tiled<false, true><<<dim3(16, GY), blk, 4 * GBUF, stream>>>(h0, slot, b3, g, M_ROWS, HD, HD);
        transpose_convert<<<dim3(18, 16, 1), blk, 0, stream>>>(W4, slot, HD, NOUT, HD, 1152);
        gemm_tiled<true, false><<<dim3(18, GY), blk, 4 * GBUF, stream>>>(g, slot, b4, out, M_ROWS, NOUT, HD);
    }
}

// Round 6
// 537.578 us; speedup vs baseline: 1.0345x; 1.0345x over previous
//
#include <hip/hip_runtime.h>
#include <hip/hip_bf16.h>
#include <math.h>

typedef __bf16 bf16_t;
typedef __bf16 bf16x8 __attribute__((ext_vector_type(8)));
typedef float f32x4 __attribute__((ext_vector_type(4)));
typedef unsigned short u16;

#define NB   40
#define NT   20
#define FEA  200
#define HD   1024
#define NOUT 1095
#define NL   12
#define M_ROWS 800      // NB*NT
#define UPITCH 196      // fp32 pitch for U in LDS (192 + 4 pad)

#define FBUF 36864      // fused ring-4 buf: A 12x1024 (rows padded 80->96) + B 24x1024
#define GBUF 24576      // dense ring-4 buf: A 16KB + B 8KB

// ---------------------------------------------------------------------------
// Transpose+convert: src fp32 logical [srcK][srcN] -> dst bf16 [Np][Kp],
// dst[n][k] = (k<srcK && n<srcN) ? src[k][n] : 0.
// Vector path (srcN%4==0): float4 loads, 4x fewer VMEM instructions
// (per-CU in-flight is instruction-count-limited). Scalar path otherwise.
// ---------------------------------------------------------------------------
__global__ __launch_bounds__(256)
void transpose_convert(const float* __restrict__ src, bf16_t* __restrict__ dst,
                       int srcK, int srcN, int Kp, int Np)
{
    __shared__ u16 tile[64 * 66];
    const int t = threadIdx.x;
    src += (size_t)blockIdx.z * srcK * srcN;
    dst += (size_t)blockIdx.z * Np * Kp;
    const int n0 = blockIdx.x << 6, k0 = blockIdx.y << 6;

    if ((srcN & 3) == 0) {
        // vector path: thread t -> 4 cols (t&15)*4, rows (t>>4) + 16j
        const int nc4 = (t & 15) << 2, kr = t >> 4;
        const int gn = n0 + nc4;
        #pragma unroll
        for (int j = 0; j < 4; j++) {
            const int gk = k0 + kr + j * 16;
            float4 v = {0.f, 0.f, 0.f, 0.f};
            if (gk < srcK && gn + 3 < srcN)
                v = *(const float4*)(src + (size_t)gk * srcN + gn);
            else if (gk < srcK) {
                float* vp = (float*)&v;
                for (int c = 0; c < 4; c++)
                    if (gn + c < srcN) vp[c] = src[(size_t)gk * srcN + gn + c];
            }
            const float* vp = (const float*)&v;
            #pragma unroll
            for (int c = 0; c < 4; c++) {
                bf16_t b = (bf16_t)vp[c];
                tile[(nc4 + c) * 66 + kr + j * 16] = *(const u16*)&b;
            }
        }
    } else {
        // scalar path (ragged srcN, e.g. 1095)
        const int nl = t & 63, kb = (t >> 6) << 4;
        const int gn = n0 + nl;
        #pragma unroll
        for (int j = 0; j < 16; j++) {
            const int gk = k0 + kb + j;
            float v = (gk < srcK && gn < srcN) ? src[(size_t)gk * srcN + gn] : 0.f;
            bf16_t b = (bf16_t)v;
            tile[nl * 66 + kb + j] = *(const u16*)&b;
        }
    }
    __syncthreads();
    {
        const int nl = t >> 2, kg = (t & 3) << 4;
        const unsigned* tp = (const unsigned*)tile;
        const int dw = nl * 33 + (kg >> 1);
        uint4 v0, v1;
        v0.x = tp[dw+0]; v0.y = tp[dw+1]; v0.z = tp[dw+2]; v0.w = tp[dw+3];
        v1.x = tp[dw+4]; v1.y = tp[dw+5]; v1.z = tp[dw+6]; v1.w = tp[dw+7];
        bf16_t* dp = dst + (size_t)(n0 + nl) * Kp + k0 + kg;
        *(uint4*)dp = v0;
        *(uint4*)(dp + 8) = v1;
    }
}

// x [800][200] fp32 -> xb [800][256] bf16, zero-padded K.
__global__ __launch_bounds__(256)
void convert_pad_x(const float* __restrict__ src, bf16_t* __restrict__ dst)
{
    const int m = blockIdx.x, k = threadIdx.x;
    dst[m * 256 + k] = (bf16_t)((k < FEA) ? src[(size_t)m * FEA + k] : 0.f);
}

// L2 prefetch snippet: warm pfnc chunks (each 64 rows x 2KB = 1024 lines) of
// pfwt at rows g*HD + n0, one dword per 128B line, keep-alive via asm.
// Loads sit AFTER the k-loop's last vmcnt clobber -> cannot perturb counts.
__device__ __forceinline__
void l2_prefetch(const bf16_t* pfwt, int pfnc, int n0, int tid)
{
    if (pfnc <= 0) return;
    unsigned pv[12];
    #pragma unroll
    for (int g = 0; g < 3; g++) {
        if (g < pfnc) {
            const char* base = (const char*)(pfwt + (size_t)(g * HD + n0) * HD);
            #pragma unroll
            for (int q = 0; q < 4; q++)
                pv[g * 4 + q] = *(const unsigned*)(base + (size_t)(q * 256 + tid) * 128);
        } else {
            #pragma unroll
            for (int q = 0; q < 4; q++) pv[g * 4 + q] = 0u;
        }
    }
    #pragma unroll
    for (int i = 0; i < 12; i++) asm volatile("" :: "v"(pv[i]));
}

// ---------------------------------------------------------------------------
// LDS-tiled dense GEMM, ring-4 counted-vmcnt pipeline (proven R4) +
// optional next-kernel L2 prefetch in the epilogue.
// ---------------------------------------------------------------------------
template<bool OUT_F32, bool RELU>
__global__ __launch_bounds__(256)
void gemm_tiled(const bf16_t* __restrict__ A, const bf16_t* __restrict__ Bt,
                const float* __restrict__ bias, void* __restrict__ C,
                int M, int Nstore, int Ks,
                const bf16_t* __restrict__ pfwt, int pfnc)
{
    extern __shared__ char lds[];           // [4][GBUF]
    const int tid = threadIdx.x;
    const int w = tid >> 6, lane = tid & 63, quad = lane >> 4, l16 = lane & 15;
    const int n0 = blockIdx.x << 6;
    const int m0 = blockIdx.y << 7;
    const int wr = w >> 1, wc = w & 1;

    const int lrow  = lane >> 3;
    const int gslot = ((lane & 7) ^ lrow) << 3;
    const bf16_t* aSrc[4];
    const bf16_t* bSrc[2];
    #pragma unroll
    for (int i = 0; i < 4; i++) {
        int r = m0 + (w * 4 + i) * 8 + lrow;
        if (r > M - 1) r = M - 1;
        aSrc[i] = A + (size_t)r * Ks + gslot;
    }
    #pragma unroll
    for (int i = 0; i < 2; i++)
        bSrc[i] = Bt + (size_t)(n0 + (w * 2 + i) * 8 + lrow) * Ks + gslot;

    f32x4 acc[4][2];
    #pragma unroll
    for (int m = 0; m < 4; m++)
        #pragma unroll
        for (int n = 0; n < 2; n++) acc[m][n] = (f32x4){0.f, 0.f, 0.f, 0.f};

    const int nkt = Ks >> 6;

    #define STAGE(kt) do {                                                     \
        const int _k0 = (kt) << 6;                                             \
        char* _b = lds + ((kt) & 3) * GBUF;                                    \
        _Pragma("unroll")                                                      \
        for (int _i = 0; _i < 4; _i++)                                         \
            __builtin_amdgcn_global_load_lds(                                  \
                (const __attribute__((address_space(1))) void*)(aSrc[_i] + _k0),\
                (__attribute__((address_space(3))) void*)(_b + (w * 4 + _i) * 1024), \
                16, 0, 0);                                                     \
        _Pragma("unroll")                                                      \
        for (int _i = 0; _i < 2; _i++)                                         \
            __builtin_amdgcn_global_load_lds(                                  \
                (const __attribute__((address_space(1))) void*)(bSrc[_i] + _k0),\
                (__attribute__((address_space(3))) void*)(_b + 16384 + (w * 2 + _i) * 1024), \
                16, 0, 0);                                                     \
    } while (0)

    STAGE(0);
    if (nkt > 1) STAGE(1);

    for (int kt = 0; kt < nkt; kt++) {
        if (kt + 2 < nkt) STAGE(kt + 2);
        const int rem = nkt - 1 - kt;
        if (rem >= 2)      asm volatile("s_waitcnt vmcnt(12)" ::: "memory");
        else if (rem == 1) asm volatile("s_waitcnt vmcnt(6)"  ::: "memory");
        else               asm volatile("s_waitcnt vmcnt(0)"  ::: "memory");
        __builtin_amdgcn_s_barrier();

        const char* ab = lds + (kt & 3) * GBUF;
        #pragma unroll
        for (int kk = 0; kk < 2; kk++) {
            const int ts = (kk << 2) + quad;
            bf16x8 a[4], b[2];
            #pragma unroll
            for (int m = 0; m < 4; m++) {
                const int r = wr * 64 + m * 16 + l16;
                a[m] = *(const bf16x8*)(ab + r * 128 + ((ts ^ (r & 7)) << 4));
            }
            #pragma unroll
            for (int n = 0; n < 2; n++) {
                const int r = wc * 32 + n * 16 + l16;
                b[n] = *(const bf16x8*)(ab + 16384 + r * 128 + ((ts ^ (r & 7)) << 4));
            }
            #pragma unroll
            for (int m = 0; m < 4; m++)
                #pragma unroll
                for (int n = 0; n < 2; n++)
                    acc[m][n] = __builtin_amdgcn_mfma_f32_16x16x32_bf16(a[m], b[n], acc[m][n], 0, 0, 0);
        }
    }
    #undef STAGE

    l2_prefetch(pfwt, pfnc, n0, tid);

    #pragma unroll
    for (int n = 0; n < 2; n++) {
        const int col = n0 + wc * 32 + n * 16 + l16;
        if (col >= Nstore) continue;
        const float bv = bias ? bias[col] : 0.f;
        #pragma unroll
        for (int m = 0; m < 4; m++) {
            #pragma unroll
            for (int i = 0; i < 4; i++) {
                const int mg = m0 + wr * 64 + m * 16 + quad * 4 + i;
                if (mg < M) {
                    float v = acc[m][n][i] + bv;
                    if (RELU) v = v > 0.f ? v : 0.f;
                    if (OUT_F32) ((float*)C)[(size_t)mg * Nstore + col] = v;
                    else         ((bf16_t*)C)[(size_t)mg * Nstore + col] = (bf16_t)v;
                }
            }
        }
    }
}

// ---------------------------------------------------------------------------
// Fused SRU layer (R4 geometry, proven): 256 thr, M=80 (4 batches) x N=192,
// K=1024, nkt=16, ring-4 counted-vmcnt (18/9/0). Epilogue: U fp32 -> LDS,
// unrolled branch-free recurrence, then next-layer L2 prefetch.
// Dynamic LDS 147456 B.
// ---------------------------------------------------------------------------
__global__ __launch_bounds__(256)
void sru_layer_fused(const bf16_t* __restrict__ hin, bf16_t* __restrict__ hout,
                     const bf16_t* __restrict__ Wt, const float* __restrict__ c0,
                     const float* __restrict__ bvec, float* __restrict__ cout,
                     const bf16_t* __restrict__ pfwt, int pfnc)
{
    extern __shared__ char lds_raw[];       // [4][FBUF]
    const int tid = threadIdx.x;
    const int w = tid >> 6, lane = tid & 63, quad = lane >> 4, l16 = lane & 15;
    const int n0 = blockIdx.x << 6;      // h-col block (16)
    const int m0 = blockIdx.y * 80;      // 4 batches   (10)

    const int lrow  = lane >> 3;
    const int gslot = ((lane & 7) ^ lrow) << 3;

    // A: 12 chunks of 8 rows (rows 80..95 clamp-dup row 79, never read back)
    const bf16_t* aSrc[3];
    #pragma unroll
    for (int i = 0; i < 3; i++) {
        int r = (w * 3 + i) * 8 + lrow;
        if (r > 79) r = 79;
        aSrc[i] = hin + (size_t)(m0 + r) * HD + gslot;
    }
    // B: 24 chunks; row rb (0..191) = Wt row (rb>>6)*HD + n0 + (rb&63)
    const bf16_t* bSrc[6];
    #pragma unroll
    for (int i = 0; i < 6; i++) {
        const int rb = (w * 6 + i) * 8 + lrow;
        bSrc[i] = Wt + (size_t)((rb >> 6) * HD + n0 + (rb & 63)) * HD + gslot;
    }

    f32x4 acc[5][3];
    #pragma unroll
    for (int m = 0; m < 5; m++)
        #pragma unroll
        for (int n = 0; n < 3; n++) acc[m][n] = (f32x4){0.f, 0.f, 0.f, 0.f};

    #define STAGEF(kt) do {                                                    \
        const int _k0 = (kt) << 6;                                             \
        char* _b = lds_raw + ((kt) & 3) * FBUF;                                \
        _Pragma("unroll")                                                      \
        for (int _i = 0; _i < 3; _i++)                                         \
            __builtin_amdgcn_global_load_lds(                                  \
                (const __attribute__((address_space(1))) void*)(aSrc[_i] + _k0), \
                (__attribute__((address_space(3))) void*)(_b + (w * 3 + _i) * 1024), \
                16, 0, 0);                                                     \
        _Pragma("unroll")                                                      \
        for (int _i = 0; _i < 6; _i++)                                         \
            __builtin_amdgcn_global_load_lds(                                  \
                (const __attribute__((address_space(1))) void*)(bSrc[_i] + _k0), \
                (__attribute__((address_space(3))) void*)(_b + 12288 + (w * 6 + _i) * 1024), \
                16, 0, 0);                                                     \
    } while (0)

    STAGEF(0);
    STAGEF(1);

    for (int kt = 0; kt < 16; kt++) {
        if (kt + 2 < 16) STAGEF(kt + 2);
        const int rem = 15 - kt;
        if (rem >= 2)      asm volatile("s_waitcnt vmcnt(18)" ::: "memory");
        else if (rem == 1) asm volatile("s_waitcnt vmcnt(9)"  ::: "memory");
        else               asm volatile("s_waitcnt vmcnt(0)"  ::: "memory");
        __builtin_amdgcn_s_barrier();

        const char* ab = lds_raw + (kt & 3) * FBUF;
        const char* bb = ab + 12288;
        #pragma unroll
        for (int kk = 0; kk < 2; kk++) {
            const int ts = (kk << 2) + quad;
            bf16x8 a[5], b[3];
            #pragma unroll
            for (int m = 0; m < 5; m++) {
                const int r = m * 16 + l16;
                a[m] = *(const bf16x8*)(ab + r * 128 + ((ts ^ (r & 7)) << 4));
            }
            #pragma unroll
            for (int n = 0; n < 3; n++) {
                const int r = (w * 3 + n) * 16 + l16;
                b[n] = *(const bf16x8*)(bb + r * 128 + ((ts ^ (r & 7)) << 4));
            }
            #pragma unroll
            for (int m = 0; m < 5; m++)
                #pragma unroll
                for (int n = 0; n < 3; n++)
                    acc[m][n] = __builtin_amdgcn_mfma_f32_16x16x32_bf16(a[m], b[n], acc[m][n], 0, 0, 0);
        }
    }
    #undef STAGEF

    __syncthreads();   // full drain before Ul overwrites the ring

    float* Ul = (float*)lds_raw;                 // [80][UPITCH]
    #pragma unroll
    for (int m = 0; m < 5; m++)
        #pragma unroll
        for (int n = 0; n < 3; n++) {
            const int col = (w * 3 + n) * 16 + l16;
            #pragma unroll
            for (int i = 0; i < 4; i++)
                Ul[(m * 16 + quad * 4 + i) * UPITCH + col] = acc[m][n][i];
        }
    __syncthreads();

    // recurrence: thread = (local batch bl 0..3, col nn); unrolled, branch-free
    const int bl = tid >> 6, nn = tid & 63, bg = blockIdx.y * 4 + bl;
    float c = c0[(size_t)bg * HD + n0 + nn];
    const float bfb = bvec[n0 + nn], brb = bvec[HD + n0 + nn];
    #pragma unroll
    for (int t = 0; t < NT; t++) {
        const float* u = &Ul[(bl * NT + t) * UPITCH];
        const float xt = u[nn];
        const float uf = u[64 + nn];
        const float ur = u[128 + nn];
        const float f = 1.f / (1.f + __expf(-(uf + bfb)));
        const float r = 1.f / (1.f + __expf(-(ur + brb)));
        c = f * c + (1.f - f) * xt;
        const float e  = __expf(-2.f * fabsf(c));
        float th = (1.f - e) / (1.f + e);
        th = (c < 0.f) ? -th : th;
        const size_t gi = (size_t)(bg * NT + t) * HD + n0 + nn;
        const float hp = (float)hin[gi];
        hout[gi] = (bf16_t)(r * th + (1.f - r) * hp);
    }

    l2_prefetch(pfwt, pfnc, n0, tid);   // warm next layer's B-slice in this XCD's L2

    cout[(size_t)bg * HD + n0 + nn] = c;
}

// ---------------------------------------------------------------------------
extern "C" void kernel_launch(void* const* d_in, const int* in_sizes, int n_in,
                              void* d_out, int out_size, void* d_ws, size_t ws_size,
                              hipStream_t stream)
{
    const float* x      = (const float*)d_in[0];
    const float* hidden = (const float*)d_in[1];
    const float* W1     = (const float*)d_in[2];
    const float* b1     = (const float*)d_in[3];
    const float* sruW   = (const float*)d_in[4];
    const float* srub   = (const float*)d_in[5];
    const float* W3     = (const float*)d_in[6];
    const float* b3     = (const float*)d_in[7];
    const float* W4     = (const float*)d_in[8];
    const float* b4     = (const float*)d_in[9];

    float* out     = (float*)d_out;
    float* hid_out = out + (size_t)M_ROWS * NOUT;          // [12,40,1024] fp32

    bf16_t* h0 = (bf16_t*)d_out;   // aliases out0 region (dead until final GEMM)

    hipFuncSetAttribute((const void*)sru_layer_fused,
                        hipFuncAttributeMaxDynamicSharedMemorySize, 4 * FBUF);
    hipFuncSetAttribute((const void*)gemm_tiled<false, false>,
                        hipFuncAttributeMaxDynamicSharedMemorySize, 4 * GBUF);
    hipFuncSetAttribute((const void*)gemm_tiled<false, true>,
                        hipFuncAttributeMaxDynamicSharedMemorySize, 4 * GBUF);
    hipFuncSetAttribute((const void*)gemm_tiled<true, false>,
                        hipFuncAttributeMaxDynamicSharedMemorySize, 4 * GBUF);

    char* ws = (char*)d_ws;
    const size_t SZ_WT  = (size_t)NL * 3 * HD * HD * 2;    // 75,497,472
    const size_t SZ_W1  = (size_t)HD * 256 * 2;
    const size_t SZ_W3  = (size_t)HD * HD * 2;
    const size_t SZ_W4  = (size_t)1152 * HD * 2;
    const size_t SZ_XB  = (size_t)M_ROWS * 256 * 2;
    const size_t SZ_H   = (size_t)M_ROWS * HD * 2;
    const size_t SLOT   = (size_t)3 * HD * HD * 2;
    const size_t FAST_NEED = SZ_WT + SZ_W1 + SZ_W3 + SZ_W4 + SZ_XB + 2 * SZ_H;
    const bool fast = ws_size >= FAST_NEED;

    const dim3 blk(256);
    const int GY = (M_ROWS + 127) >> 7;                    // 7 row-blocks

    if (fast) {
        bf16_t* wt  = (bf16_t*)ws;
        bf16_t* w1t = (bf16_t*)(ws + SZ_WT);
        bf16_t* w3t = (bf16_t*)(ws + SZ_WT + SZ_W1);
        bf16_t* w4t = (bf16_t*)(ws + SZ_WT + SZ_W1 + SZ_W3);
        bf16_t* xb  = (bf16_t*)(ws + SZ_WT + SZ_W1 + SZ_W3 + SZ_W4);
        bf16_t* h1  = (bf16_t*)(ws + SZ_WT + SZ_W1 + SZ_W3 + SZ_W4 + SZ_XB);
        bf16_t* g   = (bf16_t*)(ws + SZ_WT + SZ_W1 + SZ_W3 + SZ_W4 + SZ_XB + SZ_H);

        convert_pad_x<<<M_ROWS, blk, 0, stream>>>(x, xb);
        transpose_convert<<<dim3(16, 4, 1),  blk, 0, stream>>>(W1,   w1t, FEA, HD,    256, HD);
        transpose_convert<<<dim3(48, 16, NL), blk, 0, stream>>>(sruW, wt,  HD,  3*HD, HD,  3*HD);
        transpose_convert<<<dim3(16, 16, 1), blk, 0, stream>>>(W3,   w3t, HD,  HD,   HD,  HD);
        transpose_convert<<<dim3(18, 16, 1), blk, 0, stream>>>(W4,   w4t, HD,  NOUT, HD,  1152);

        // gemm1 warms layer-0 weights
        gemm_tiled<false, false><<<dim3(16, GY), blk, 4 * GBUF, stream>>>(
            xb, w1t, b1, h0, M_ROWS, HD, 256, wt, 3);

        for (int l = 0; l < NL; l++) {
            const bf16_t* hi = (l & 1) ? h1 : h0;
            bf16_t*       ho = (l & 1) ? h0 : h1;
            const bf16_t* pfw = (l + 1 < NL) ? wt + (size_t)(l + 1) * 3 * HD * HD : w3t;
            const int     pfn = (l + 1 < NL) ? 3 : 1;
            sru_layer_fused<<<dim3(16, 10), blk, 4 * FBUF, stream>>>(
                hi, ho, wt + (size_t)l * 3 * HD * HD,
                hidden + (size_t)l * NB * HD, srub + (size_t)l * 2 * HD,
                hid_out + (size_t)l * NB * HD, pfw, pfn);
        }
        // gemm3 warms w4t (first 1024 of 1152 rows)
        gemm_tiled<false, true><<<dim3(16, GY), blk, 4 * GBUF, stream>>>(
            h0, w3t, b3, g, M_ROWS, HD, HD, w4t, 1);
        gemm_tiled<true, false><<<dim3(18, GY), blk, 4 * GBUF, stream>>>(
            g, w4t, b4, out, M_ROWS, NOUT, HD, (const bf16_t*)0, 0);
    } else {
        bf16_t* slot = (bf16_t*)ws;
        bf16_t* xb   = (bf16_t*)(ws + SLOT);
        bf16_t* h1   = (bf16_t*)(ws + SLOT + SZ_XB);
        bf16_t* g    = (bf16_t*)(ws + SLOT + SZ_XB + SZ_H);

        convert_pad_x<<<M_ROWS, blk, 0, stream>>>(x, xb);
        transpose_convert<<<dim3(16, 4, 1), blk, 0, stream>>>(W1, slot, FEA, HD, 256, HD);
        gemm_tiled<false, false><<<dim3(16, GY), blk, 4 * GBUF, stream>>>(
            xb, slot, b1, h0, M_ROWS, HD, 256, (const bf16_t*)0, 0);

        for (int l = 0; l < NL; l++) {
            transpose_convert<<<dim3(48, 16, 1), blk, 0, stream>>>(
                sruW + (size_t)l * HD * 3 * HD, slot, HD, 3*HD, HD, 3*HD);
            const bf16_t* hi = (l & 1) ? h1 : h0;
            bf16_t*       ho = (l & 1) ? h0 : h1;
            sru_layer_fused<<<dim3(16, 10), blk, 4 * FBUF, stream>>>(
                hi, ho, slot,
                hidden + (size_t)l * NB * HD, srub + (size_t)l * 2 * HD,
                hid_out + (size_t)l * NB * HD, (const bf16_t*)0, 0);
        }
        transpose_convert<<<dim3(16, 16, 1), blk, 0, stream>>>(W3, slot, HD, HD, HD, HD);
        gemm_tiled<false, true><<<dim3(16, GY), blk, 4 * GBUF, stream>>>(
            h0, slot, b3, g, M_ROWS, HD, HD, (const bf16_t*)0, 0);
        transpose_convert<<<dim3(18, 16, 1), blk, 0, stream>>>(W4, slot, HD, NOUT, HD, 1152);
        gemm_tiled<true, false><<<dim3(18, GY), blk, 4 * GBUF, stream>>>(
            g, slot, b4, out, M_ROWS, NOUT, HD, (const bf16_t*)0, 0);
    }
}